// Round 17
// baseline (179.245 us; speedup 1.0000x reference)
//
#include <hip/hip_runtime.h>
#include <hip/hip_bf16.h>

typedef _Float16 f16;
typedef _Float16 f16x8 __attribute__((ext_vector_type(8)));
typedef _Float16 f16x4 __attribute__((ext_vector_type(4)));
typedef float f32x4 __attribute__((ext_vector_type(4)));

constexpr int Bb = 8, Ss = 1024, Hh = 16, DH = 64, DM = 1024, N3 = 3072;
constexpr int Mm = Bb * Ss;  // 8192
constexpr float EPS = 1.1920929e-07f;

// async global->LDS, 16B per lane; LDS dest is wave-uniform base + lane*16
__device__ __forceinline__ void gll16(const f16* g, f16* l) {
    __builtin_amdgcn_global_load_lds(
        (__attribute__((address_space(1))) void*)(g),
        (__attribute__((address_space(3))) void*)(l), 16, 0, 0);
}

// ---------------- K0: fused {RMSNorm+cast} and {weight casts + row permute} ----------------
__global__ void prep_kernel(const float* __restrict__ x, f16* __restrict__ xh,
                            const float* __restrict__ Wqkv, const float* __restrict__ Wo,
                            f16* __restrict__ wq, f16* __restrict__ wo) {
    const int t = threadIdx.x;
    const int blk = blockIdx.x;
    if (blk < Mm) {
        const int row = blk;
        float4 v = *(const float4*)(x + (size_t)row * DM + t * 4);
        float s = v.x * v.x + v.y * v.y + v.z * v.z + v.w * v.w;
#pragma unroll
        for (int o = 32; o > 0; o >>= 1) s += __shfl_down(s, o, 64);
        __shared__ float red[4];
        if ((t & 63) == 0) red[t >> 6] = s;
        __syncthreads();
        float tot = red[0] + red[1] + red[2] + red[3];
        float sc = rsqrtf(tot * (1.0f / DM) + EPS);
        f16x4 hv = {(f16)(v.x * sc), (f16)(v.y * sc), (f16)(v.z * sc), (f16)(v.w * sc)};
        *(f16x4*)(xh + (size_t)row * DM + t * 4) = hv;
    } else if (blk < Mm + N3) {
        int j = blk - Mm;  // source row: j = h*192 + d*3 + which
        int h = j / 192, r = j % 192, d = r / 3, wh = r % 3;
        int rp = wh * 1024 + h * 64 + d;  // permuted dst row
        float4 v = *(const float4*)(Wqkv + (size_t)j * DM + t * 4);
        f16x4 hv = {(f16)v.x, (f16)v.y, (f16)v.z, (f16)v.w};
        *(f16x4*)(wq + (size_t)rp * DM + t * 4) = hv;
    } else {
        int j = blk - Mm - N3;
        float4 v = *(const float4*)(Wo + (size_t)j * DM + t * 4);
        f16x4 hv = {(f16)v.x, (f16)v.y, (f16)v.z, (f16)v.w};
        *(f16x4*)(wo + (size_t)j * DM + t * 4) = hv;
    }
}

// ---------------- K2: QKV GEMM (m97 + permuted cols + LDS-transpose epilogue) ----------------
__launch_bounds__(256, 4)
__global__ void qkv_gemm(const f16* __restrict__ xh, const f16* __restrict__ wq,
                         const float* __restrict__ bqkv, f16* __restrict__ qk,
                         f16* __restrict__ vT) {
    __shared__ __align__(16) f16 smem[17536];  // As(8192) + Bs(8192); reused as Cs
    f16* As = smem;
    f16* Bs = smem + 8192;
    f16* Cs = smem;
    const int t = threadIdx.x, lane = t & 63, w = t >> 6;
    const int bid = blockIdx.y * gridDim.x + blockIdx.x;
    const int swz = (bid & 7) * 192 + (bid >> 3);
    const int gm0 = (swz / 24) * 128, gn0 = (swz % 24) * 128;
    const int wm = (w >> 1) * 64, wn = (w & 1) * 64;
    const int srow = lane >> 3, sslot = (lane & 7) ^ srow;
    const int r15 = lane & 15, cs = lane >> 4;

    const f16* Ag = xh + (size_t)(gm0 + srow) * DM + sslot * 8;
    const f16* Bg = wq + (size_t)(gn0 + srow) * DM + sslot * 8;

    int aoff[4][2], boff[4][2];
#pragma unroll
    for (int i = 0; i < 4; ++i) {
        int Ra = wm + i * 16 + r15;
        aoff[i][0] = Ra * 64 + ((cs ^ (Ra & 7)) * 8);
        aoff[i][1] = Ra * 64 + (((cs + 4) ^ (Ra & 7)) * 8);
        int Rb = wn + i * 16 + r15;
        boff[i][0] = Rb * 64 + ((cs ^ (Rb & 7)) * 8);
        boff[i][1] = Rb * 64 + (((cs + 4) ^ (Rb & 7)) * 8);
    }
    f32x4 acc[4][4] = {};

    for (int k0 = 0; k0 < DM; k0 += 64) {
        __syncthreads();
#pragma unroll
        for (int j = 0; j < 4; ++j) {
            int c = w * 4 + j;
            gll16(Ag + (size_t)c * 8 * DM + k0, As + c * 512);
            gll16(Bg + (size_t)c * 8 * DM + k0, Bs + c * 512);
        }
        __syncthreads();
#pragma unroll
        for (int half = 0; half < 2; ++half) {
            f16x8 af[4], bf[4];
#pragma unroll
            for (int i = 0; i < 4; ++i) af[i] = *(const f16x8*)&As[aoff[i][half]];
#pragma unroll
            for (int i = 0; i < 4; ++i) bf[i] = *(const f16x8*)&Bs[boff[i][half]];
#pragma unroll
            for (int mi = 0; mi < 4; ++mi)
#pragma unroll
                for (int ni = 0; ni < 4; ++ni)
                    acc[mi][ni] = __builtin_amdgcn_mfma_f32_16x16x32_f16(af[mi], bf[ni], acc[mi][ni], 0, 0, 0);
        }
    }

    // ---- epilogue: LDS transpose, coalesced f16x8 stores ----
    const int which = gn0 >> 10;  // block-uniform
    const int CSTR = (which == 2) ? 137 : 136;
    __syncthreads();
#pragma unroll
    for (int ni = 0; ni < 4; ++ni) {
        int jcolp = gn0 + wn + ni * 16 + r15;
        int rr = jcolp & 1023, hh = rr >> 6, dd = rr & 63;
        float bb = bqkv[hh * 192 + dd * 3 + which];
#pragma unroll
        for (int mi = 0; mi < 4; ++mi)
#pragma unroll
            for (int jj = 0; jj < 4; ++jj)
                Cs[(wm + mi * 16 + cs * 4 + jj) * CSTR + (wn + ni * 16 + r15)] =
                    (f16)(acc[mi][ni][jj] + bb);
    }
    __syncthreads();
    const int bglob = gm0 >> 10;
    const int sbase = gm0 & 1023;
    if (which < 2) {
        f16* dstb = qk + (size_t)which * (Bb * Hh) * (Ss * DH);
#pragma unroll
        for (int it = 0; it < 8; ++it) {
            int lin = it * 2048 + t * 8;
            int row = lin >> 7, c0 = lin & 127;
            f16x8 v = *(const f16x8*)&Cs[row * 136 + c0];
            int rr = (gn0 + c0) & 1023;
            int hh = rr >> 6, d0 = rr & 63;
            *(f16x8*)(dstb + ((size_t)(bglob * Hh + hh)) * (Ss * DH) +
                      (size_t)(sbase + row) * DH + d0) = v;
        }
    } else {
#pragma unroll
        for (int it = 0; it < 8; ++it) {
            int col = it * 16 + (t >> 4);
            int s0 = (t & 15) * 8;
            f16x8 v;
#pragma unroll
            for (int e = 0; e < 8; ++e) v[e] = Cs[(s0 + e) * 137 + col];
            int rr = (gn0 + col) & 1023;
            int hh = rr >> 6, dd = rr & 63;
            *(f16x8*)(vT + ((size_t)(bglob * Hh + hh) * DH + dd) * Ss + sbase + s0) = v;
        }
    }
}

// ---------------- K3a: column stats; 128-row Q chunks, dbuf, paired strips ----------------
// grid: (4, 128) x 512 threads; paired k-strips (si, 7-si)
__launch_bounds__(512, 2)
__global__ void colstats_kernel(const f16* __restrict__ qk, float* __restrict__ cbuf) {
    __shared__ __align__(16) f16 Qs[2][128 * 64];  // 32KB
    const int t = threadIdx.x, lane = t & 63, w = t >> 6;
    const int r15 = lane & 15, cs = lane >> 4;
    const int srow = lane >> 3, sslot = (lane & 7) ^ srow;
    const int bh = blockIdx.y, si = blockIdx.x;
    const int kA0 = si * 128, kB0 = (7 - si) * 128;
    const size_t hs = (size_t)(Bb * Hh) * (Ss * DH);
    const f16* qb = qk + (size_t)bh * (Ss * DH);
    const f16* kb = qb + hs;

    const int kwA = kA0 + w * 16, kglobA = kwA + r15;
    const int kwB = kB0 + w * 16, kglobB = kwB + r15;
    f16x8 kfA0 = *(const f16x8*)(kb + (size_t)(kwA + r15) * DH + cs * 8);
    f16x8 kfA1 = *(const f16x8*)(kb + (size_t)(kwA + r15) * DH + 32 + cs * 8);
    f16x8 kfB0 = *(const f16x8*)(kb + (size_t)(kwB + r15) * DH + cs * 8);
    f16x8 kfB1 = *(const f16x8*)(kb + (size_t)(kwB + r15) * DH + 32 + cs * 8);

    gll16(qb + (size_t)(si * 128 + w * 16 + srow) * DH + sslot * 8, Qs[0] + (2 * w) * 512);
    gll16(qb + (size_t)(si * 128 + w * 16 + 8 + srow) * DH + sslot * 8, Qs[0] + (2 * w + 1) * 512);
    __syncthreads();
    float la = 0.0f, lb = 0.0f;
    int cur = 0;

    for (int qt2 = si; qt2 < 8; ++qt2) {
        if (qt2 + 1 < 8) {
            gll16(qb + (size_t)((qt2 + 1) * 128 + w * 16 + srow) * DH + sslot * 8,
                  Qs[cur ^ 1] + (2 * w) * 512);
            gll16(qb + (size_t)((qt2 + 1) * 128 + w * 16 + 8 + srow) * DH + sslot * 8,
                  Qs[cur ^ 1] + (2 * w + 1) * 512);
        }
#pragma unroll
        for (int qs = 0; qs < 8; ++qs) {
            const int qb16 = qt2 * 128 + qs * 16;
            const bool nA = (qb16 + 15 >= kwA);
            const bool nB = (qb16 + 15 >= kwB);
            if (!(nA || nB)) continue;
            int Ra = qs * 16 + r15;
            f16x8 a0 = *(const f16x8*)&Qs[cur][Ra * 64 + ((cs ^ (Ra & 7)) * 8)];
            f16x8 a1 = *(const f16x8*)&Qs[cur][Ra * 64 + (((cs + 4) ^ (Ra & 7)) * 8)];
            if (nA) {
                f32x4 sf = {};
                sf = __builtin_amdgcn_mfma_f32_16x16x32_f16(a0, kfA0, sf, 0, 0, 0);
                sf = __builtin_amdgcn_mfma_f32_16x16x32_f16(a1, kfA1, sf, 0, 0, 0);
#pragma unroll
                for (int j = 0; j < 4; ++j) {
                    int q = qb16 + cs * 4 + j;
                    la += (q >= kglobA) ? __expf(sf[j]) : 0.0f;
                }
            }
            if (nB) {
                f32x4 sf = {};
                sf = __builtin_amdgcn_mfma_f32_16x16x32_f16(a0, kfB0, sf, 0, 0, 0);
                sf = __builtin_amdgcn_mfma_f32_16x16x32_f16(a1, kfB1, sf, 0, 0, 0);
#pragma unroll
                for (int j = 0; j < 4; ++j) {
                    int q = qb16 + cs * 4 + j;
                    lb += (q >= kglobB) ? __expf(sf[j]) : 0.0f;
                }
            }
        }
        __syncthreads();
        cur ^= 1;
    }
    la += __shfl_xor(la, 16, 64);
    la += __shfl_xor(la, 32, 64);
    lb += __shfl_xor(lb, 16, 64);
    lb += __shfl_xor(lb, 32, 64);
    if (cs == 0) {
        cbuf[bh * Ss + kglobA] = logf(la);
        cbuf[bh * Ss + kglobB] = logf(lb);
    }
}

// ---------------- K3b: attnz; Q-frags direct to reg, K/V staged + shared, setprio ----------------
// grid: (4, 128) x 512 threads; paired q-strips (si, 7-si)
__launch_bounds__(512, 2)
__global__ void attnz_kernel(const f16* __restrict__ qk, const f16* __restrict__ vT,
                             const float* __restrict__ cbuf, f16* __restrict__ z) {
    __shared__ __align__(16) f16 Ks[64 * 64];
    __shared__ __align__(16) f16 Vs[64 * 64];
    __shared__ __align__(16) float cb[1024];
    const int t = threadIdx.x, lane = t & 63, w = t >> 6;
    const int r15 = lane & 15, cs = lane >> 4;
    const int srow = lane >> 3, sslot = (lane & 7) ^ srow;
    const int bh = blockIdx.y, si = blockIdx.x;
    const int qtA = si, qtB = 7 - si;
    const size_t hs = (size_t)(Bb * Hh) * (Ss * DH);
    const f16* qb = qk + (size_t)bh * (Ss * DH);
    const f16* kb = qb + hs;
    const f16* vb = vT + (size_t)bh * (DH * Ss);

    const int qwA = qtA * 128 + w * 16, qA = qwA + r15;
    const int qwB = qtB * 128 + w * 16, qB = qwB + r15;
    f16x8 aqA0 = *(const f16x8*)(qb + (size_t)(qwA + r15) * DH + cs * 8);
    f16x8 aqA1 = *(const f16x8*)(qb + (size_t)(qwA + r15) * DH + 32 + cs * 8);
    f16x8 aqB0 = *(const f16x8*)(qb + (size_t)(qwB + r15) * DH + cs * 8);
    f16x8 aqB1 = *(const f16x8*)(qb + (size_t)(qwB + r15) * DH + 32 + cs * 8);

    gll16(kb + (size_t)(w * 8 + srow) * DH + sslot * 8, Ks + w * 512);
    gll16(vb + (size_t)(w * 8 + srow) * Ss + sslot * 8, Vs + w * 512);
    {
        float2 c2 = *(const float2*)(cbuf + bh * Ss + t * 2);
        *(float2*)&cb[t * 2] = c2;
    }
    __syncthreads();
    f32x4 accA[4] = {}, accB[4] = {};
    const int nktA = 2 * qtA + 2, nktB = 2 * qtB + 2;
    const int sAl = ((cs & 1) * 2) * 16 + r15;
    const int sBl = sAl + 16;
    const bool hi = (cs >> 1) != 0;

    for (int kt = 0; kt < nktB; ++kt) {
        if (kt) {
            __syncthreads();
            gll16(kb + (size_t)(kt * 64 + w * 8 + srow) * DH + sslot * 8, Ks + w * 512);
            gll16(vb + (size_t)(w * 8 + srow) * Ss + kt * 64 + sslot * 8, Vs + w * 512);
            __syncthreads();
        }
        const int kb0 = kt * 64;
        const bool doA = (kt < nktA) && (kb0 <= qwA + 15);
        const bool doB = (kb0 <= qwB + 15);
        if (!(doA || doB)) continue;

        unsigned pkA[4][2], pkB[4][2];
#pragma unroll
        for (int tl = 0; tl < 4; ++tl) {
            const int kbase = kb0 + tl * 16;
            const bool nA = doA && (kbase <= qwA + 15);
            const bool nB = doB && (kbase <= qwB + 15);
            pkA[tl][0] = 0u; pkA[tl][1] = 0u;
            pkB[tl][0] = 0u; pkB[tl][1] = 0u;
            if (!(nA || nB)) continue;
            int Rk2 = tl * 16 + r15;
            f16x8 kf0 = *(const f16x8*)&Ks[Rk2 * 64 + ((cs ^ (Rk2 & 7)) * 8)];
            f16x8 kf1 = *(const f16x8*)&Ks[Rk2 * 64 + (((cs + 4) ^ (Rk2 & 7)) * 8)];
            f32x4 cv = *(const f32x4*)&cb[kbase + cs * 4];
            if (nA) {
                f32x4 sf = {};
                __builtin_amdgcn_s_setprio(1);
                sf = __builtin_amdgcn_mfma_f32_16x16x32_f16(kf0, aqA0, sf, 0, 0, 0);
                sf = __builtin_amdgcn_mfma_f32_16x16x32_f16(kf1, aqA1, sf, 0, 0, 0);
                __builtin_amdgcn_s_setprio(0);
                f16 p[4];
#pragma unroll
                for (int j = 0; j < 4; ++j) {
                    int k = kbase + cs * 4 + j;
                    p[j] = (f16)((k <= qA) ? __expf(sf[j] - cv[j]) : 0.0f);
                }
                union { f16 h[2]; unsigned u; } u0, u1;
                u0.h[0] = p[0]; u0.h[1] = p[1];
                u1.h[0] = p[2]; u1.h[1] = p[3];
                pkA[tl][0] = u0.u; pkA[tl][1] = u1.u;
            }
            if (nB) {
                f32x4 sf = {};
                __builtin_amdgcn_s_setprio(1);
                sf = __builtin_amdgcn_mfma_f32_16x16x32_f16(kf0, aqB0, sf, 0, 0, 0);
                sf = __builtin_amdgcn_mfma_f32_16x16x32_f16(kf1, aqB1, sf, 0, 0, 0);
                __builtin_amdgcn_s_setprio(0);
                f16 p[4];
#pragma unroll
                for (int j = 0; j < 4; ++j) {
                    int k = kbase + cs * 4 + j;
                    p[j] = (f16)((k <= qB) ? __expf(sf[j] - cv[j]) : 0.0f);
                }
                union { f16 h[2]; unsigned u; } u0, u1;
                u0.h[0] = p[0]; u0.h[1] = p[1];
                u1.h[0] = p[2]; u1.h[1] = p[3];
                pkB[tl][0] = u0.u; pkB[tl][1] = u1.u;
            }
        }
        f16x8 bfA[2], bfB[2];
        bool uA[2], uB[2];
#pragma unroll
        for (int c = 0; c < 2; ++c) {
            uA[c] = doA && (kb0 + c * 32 <= qwA + 15);
            uB[c] = doB && (kb0 + c * 32 <= qwB + 15);
            if (uA[c]) {
                unsigned a0 = (unsigned)__shfl((int)pkA[2 * c][0], sAl, 64);
                unsigned a1 = (unsigned)__shfl((int)pkA[2 * c][1], sAl, 64);
                unsigned a2 = (unsigned)__shfl((int)pkA[2 * c][0], sBl, 64);
                unsigned a3 = (unsigned)__shfl((int)pkA[2 * c][1], sBl, 64);
                unsigned b0_ = (unsigned)__shfl((int)pkA[2 * c + 1][0], sAl, 64);
                unsigned b1_ = (unsigned)__shfl((int)pkA[2 * c + 1][1], sAl, 64);
                unsigned b2_ = (unsigned)__shfl((int)pkA[2 * c + 1][0], sBl, 64);
                unsigned b3_ = (unsigned)__shfl((int)pkA[2 * c + 1][1], sBl, 64);
                union { unsigned u[4]; f16x8 v; } bf;
                bf.u[0] = hi ? b0_ : a0;
                bf.u[1] = hi ? b1_ : a1;
                bf.u[2] = hi ? b2_ : a2;
                bf.u[3] = hi ? b3_ : a3;
                bfA[c] = bf.v;
            }
            if (uB[c]) {
                unsigned a0 = (unsigned)__shfl((int)pkB[2 * c][0], sAl, 64);
                unsigned a1 = (unsigned)__shfl((int)pkB[2 * c][1], sAl, 64);
                unsigned a2 = (unsigned)__shfl((int)pkB[2 * c][0], sBl, 64);
                unsigned a3 = (unsigned)__shfl((int)pkB[2 * c][1], sBl, 64);
                unsigned b0_ = (unsigned)__shfl((int)pkB[2 * c + 1][0], sAl, 64);
                unsigned b1_ = (unsigned)__shfl((int)pkB[2 * c + 1][1], sAl, 64);
                unsigned b2_ = (unsigned)__shfl((int)pkB[2 * c + 1][0], sBl, 64);
                unsigned b3_ = (unsigned)__shfl((int)pkB[2 * c + 1][1], sBl, 64);
                union { unsigned u[4]; f16x8 v; } bf;
                bf.u[0] = hi ? b0_ : a0;
                bf.u[1] = hi ? b1_ : a1;
                bf.u[2] = hi ? b2_ : a2;
                bf.u[3] = hi ? b3_ : a3;
                bfB[c] = bf.v;
            }
        }
        __builtin_amdgcn_s_setprio(1);
#pragma unroll
        for (int dt = 0; dt < 4; ++dt) {
            int Rv = dt * 16 + r15;
            f16x8 v0 = *(const f16x8*)&Vs[Rv * 64 + ((cs ^ (Rv & 7)) * 8)];
            f16x8 v1 = *(const f16x8*)&Vs[Rv * 64 + (((4 + cs) ^ (Rv & 7)) * 8)];
            if (uA[0]) accA[dt] = __builtin_amdgcn_mfma_f32_16x16x32_f16(v0, bfA[0], accA[dt], 0, 0, 0);
            if (uA[1]) accA[dt] = __builtin_amdgcn_mfma_f32_16x16x32_f16(v1, bfA[1], accA[dt], 0, 0, 0);
            if (uB[0]) accB[dt] = __builtin_amdgcn_mfma_f32_16x16x32_f16(v0, bfB[0], accB[dt], 0, 0, 0);
            if (uB[1]) accB[dt] = __builtin_amdgcn_mfma_f32_16x16x32_f16(v1, bfB[1], accB[dt], 0, 0, 0);
        }
        __builtin_amdgcn_s_setprio(0);
    }
    const int b = bh >> 4, h = bh & 15;
#pragma unroll
    for (int dt = 0; dt < 4; ++dt) {
        f16x4 zvA = {(f16)accA[dt][0], (f16)accA[dt][1], (f16)accA[dt][2], (f16)accA[dt][3]};
        *(f16x4*)(z + ((size_t)(b * Ss + qA)) * DM + h * DH + dt * 16 + cs * 4) = zvA;
        f16x4 zvB = {(f16)accB[dt][0], (f16)accB[dt][1], (f16)accB[dt][2], (f16)accB[dt][3]};
        *(f16x4*)(z + ((size_t)(b * Ss + qB)) * DM + h * DH + dt * 16 + cs * 4) = zvB;
    }
}

// ---------------- K4: output projection (m97 + f16 LDS-transpose epilogue, 4 blk/CU) ----------------
__launch_bounds__(256, 4)
__global__ void out_gemm(const f16* __restrict__ z, const f16* __restrict__ wo,
                         const float* __restrict__ bo, float* __restrict__ out) {
    __shared__ __align__(16) f16 smem[17408];  // As(8192)+Bs(8192); reused as Cs f16[128][136]
    f16* As = smem;
    f16* Bs = smem + 8192;
    f16* Cs = smem;
    const int t = threadIdx.x, lane = t & 63, w = t >> 6;
    const int bid = blockIdx.y * gridDim.x + blockIdx.x;
    const int swz = (bid & 7) * 64 + (bid >> 3);
    const int gm0 = (swz / 8) * 128, gn0 = (swz % 8) * 128;
    const int wm = (w >> 1) * 64, wn = (w & 1) * 64;
    const int srow = lane >> 3, sslot = (lane & 7) ^ srow;
    const int r15 = lane & 15, cs = lane >> 4;

    const f16* Ag = z + (size_t)(gm0 + srow) * DM + sslot * 8;
    const f16* Bg = wo + (size_t)(gn0 + srow) * DM + sslot * 8;

    int aoff[4][2], boff[4][2];
#pragma unroll
    for (int i = 0; i < 4; ++i) {
        int Ra = wm + i * 16 + r15;
        aoff[i][0] = Ra * 64 + ((cs ^ (Ra & 7)) * 8);
        aoff[i][1] = Ra * 64 + (((cs + 4) ^ (Ra & 7)) * 8);
        int Rb = wn + i * 16 + r15;
        boff[i][0] = Rb * 64 + ((cs ^ (Rb & 7)) * 8);
        boff[i][1] = Rb * 64 + (((cs + 4) ^ (Rb & 7)) * 8);
    }
    f32x4 acc[4][4] = {};

    for (int k0 = 0; k0 < DM; k0 += 64) {
        __syncthreads();
#pragma unroll
        for (int j = 0; j < 4; ++j) {
            int c = w * 4 + j;
            gll16(Ag + (size_t)c * 8 * DM + k0, As + c * 512);
            gll16(Bg + (size_t)c * 8 * DM + k0, Bs + c * 512);
        }
        __syncthreads();
#pragma unroll
        for (int half = 0; half < 2; ++half) {
            f16x8 af[4], bf[4];
#pragma unroll
            for (int i = 0; i < 4; ++i) af[i] = *(const f16x8*)&As[aoff[i][half]];
#pragma unroll
            for (int i = 0; i < 4; ++i) bf[i] = *(const f16x8*)&Bs[boff[i][half]];
#pragma unroll
            for (int mi = 0; mi < 4; ++mi)
#pragma unroll
                for (int ni = 0; ni < 4; ++ni)
                    acc[mi][ni] = __builtin_amdgcn_mfma_f32_16x16x32_f16(af[mi], bf[ni], acc[mi][ni], 0, 0, 0);
        }
    }
    // ---- epilogue: f16 LDS transpose -> coalesced float4 stores ----
    __syncthreads();
#pragma unroll
    for (int ni = 0; ni < 4; ++ni) {
        float bb = bo[gn0 + wn + ni * 16 + r15];
#pragma unroll
        for (int mi = 0; mi < 4; ++mi)
#pragma unroll
            for (int jj = 0; jj < 4; ++jj)
                Cs[(wm + mi * 16 + cs * 4 + jj) * 136 + (wn + ni * 16 + r15)] =
                    (f16)(acc[mi][ni][jj] + bb);
    }
    __syncthreads();
#pragma unroll
    for (int it = 0; it < 8; ++it) {
        int lin = it * 2048 + t * 8;
        int row = lin >> 7, c0 = lin & 127;
        f16x8 v = *(const f16x8*)&Cs[row * 136 + c0];
        float4 lo = {(float)v[0], (float)v[1], (float)v[2], (float)v[3]};
        float4 hi4 = {(float)v[4], (float)v[5], (float)v[6], (float)v[7]};
        float* dst = out + (size_t)(gm0 + row) * DM + gn0 + c0;
        *(float4*)dst = lo;
        *(float4*)(dst + 4) = hi4;
    }
}

extern "C" void kernel_launch(void* const* d_in, const int* in_sizes, int n_in,
                              void* d_out, int out_size, void* d_ws, size_t ws_size,
                              hipStream_t stream) {
    (void)in_sizes; (void)n_in; (void)out_size; (void)ws_size;
    const float* x    = (const float*)d_in[0];
    const float* Wqkv = (const float*)d_in[1];
    const float* bqkv = (const float*)d_in[2];
    const float* Wo   = (const float*)d_in[3];
    const float* bo   = (const float*)d_in[4];
    float* out = (float*)d_out;

    char* ws = (char*)d_ws;
    f16* xh   = (f16*)ws;                       // 16,777,216
    f16* z    = (f16*)ws;                       // reuse (xh dead after qkv gemm)
    f16* wq   = (f16*)(ws + 16777216);          //  6,291,456 (row-permuted)
    f16* wo   = (f16*)(ws + 23068672);          //  2,097,152
    f16* qk   = (f16*)(ws + 25165824);          // 33,554,432
    f16* vT   = (f16*)(ws + 58720256);          // 16,777,216
    float* cbuf = (float*)(ws + 75497472);      //    524,288

    prep_kernel<<<Mm + N3 + DM, 256, 0, stream>>>(x, xh, Wqkv, Wo, wq, wo);
    qkv_gemm<<<dim3(N3 / 128, Mm / 128), 256, 0, stream>>>(xh, wq, bqkv, qk, vT);
    colstats_kernel<<<dim3(4, Bb * Hh), 512, 0, stream>>>(qk, cbuf);
    attnz_kernel<<<dim3(4, Bb * Hh), 512, 0, stream>>>(qk, vT, cbuf, z);
    out_gemm<<<dim3(DM / 128, Mm / 128), 256, 0, stream>>>(z, wo, bo, out);
}

// Round 18
// 174.290 us; speedup vs baseline: 1.0284x; 1.0284x over previous
//
#include <hip/hip_runtime.h>
#include <hip/hip_bf16.h>

typedef _Float16 f16;
typedef _Float16 f16x8 __attribute__((ext_vector_type(8)));
typedef _Float16 f16x4 __attribute__((ext_vector_type(4)));
typedef float f32x4 __attribute__((ext_vector_type(4)));

constexpr int Bb = 8, Ss = 1024, Hh = 16, DH = 64, DM = 1024, N3 = 3072;
constexpr int Mm = Bb * Ss;  // 8192
constexpr float EPS = 1.1920929e-07f;

// async global->LDS, 16B per lane; LDS dest is wave-uniform base + lane*16
__device__ __forceinline__ void gll16(const f16* g, f16* l) {
    __builtin_amdgcn_global_load_lds(
        (__attribute__((address_space(1))) void*)(g),
        (__attribute__((address_space(3))) void*)(l), 16, 0, 0);
}

// ---------------- K0: fused {RMSNorm+cast} and {weight casts + row permute} ----------------
__global__ void prep_kernel(const float* __restrict__ x, f16* __restrict__ xh,
                            const float* __restrict__ Wqkv, const float* __restrict__ Wo,
                            f16* __restrict__ wq, f16* __restrict__ wo) {
    const int t = threadIdx.x;
    const int blk = blockIdx.x;
    if (blk < Mm) {
        const int row = blk;
        float4 v = *(const float4*)(x + (size_t)row * DM + t * 4);
        float s = v.x * v.x + v.y * v.y + v.z * v.z + v.w * v.w;
#pragma unroll
        for (int o = 32; o > 0; o >>= 1) s += __shfl_down(s, o, 64);
        __shared__ float red[4];
        if ((t & 63) == 0) red[t >> 6] = s;
        __syncthreads();
        float tot = red[0] + red[1] + red[2] + red[3];
        float sc = rsqrtf(tot * (1.0f / DM) + EPS);
        f16x4 hv = {(f16)(v.x * sc), (f16)(v.y * sc), (f16)(v.z * sc), (f16)(v.w * sc)};
        *(f16x4*)(xh + (size_t)row * DM + t * 4) = hv;
    } else if (blk < Mm + N3) {
        int j = blk - Mm;  // source row: j = h*192 + d*3 + which
        int h = j / 192, r = j % 192, d = r / 3, wh = r % 3;
        int rp = wh * 1024 + h * 64 + d;  // permuted dst row
        float4 v = *(const float4*)(Wqkv + (size_t)j * DM + t * 4);
        f16x4 hv = {(f16)v.x, (f16)v.y, (f16)v.z, (f16)v.w};
        *(f16x4*)(wq + (size_t)rp * DM + t * 4) = hv;
    } else {
        int j = blk - Mm - N3;
        float4 v = *(const float4*)(Wo + (size_t)j * DM + t * 4);
        f16x4 hv = {(f16)v.x, (f16)v.y, (f16)v.z, (f16)v.w};
        *(f16x4*)(wo + (size_t)j * DM + t * 4) = hv;
    }
}

// ---------------- K2: QKV GEMM (m97 + permuted cols + LDS-transpose epilogue) ----------------
__launch_bounds__(256, 2)
__global__ void qkv_gemm(const f16* __restrict__ xh, const f16* __restrict__ wq,
                         const float* __restrict__ bqkv, f16* __restrict__ qk,
                         f16* __restrict__ vT) {
    __shared__ __align__(16) f16 smem[17536];  // As(8192) + Bs(8192); reused as Cs
    f16* As = smem;
    f16* Bs = smem + 8192;
    f16* Cs = smem;
    const int t = threadIdx.x, lane = t & 63, w = t >> 6;
    const int bid = blockIdx.y * gridDim.x + blockIdx.x;
    const int swz = (bid & 7) * 192 + (bid >> 3);
    const int gm0 = (swz / 24) * 128, gn0 = (swz % 24) * 128;
    const int wm = (w >> 1) * 64, wn = (w & 1) * 64;
    const int srow = lane >> 3, sslot = (lane & 7) ^ srow;
    const int r15 = lane & 15, cs = lane >> 4;

    const f16* Ag = xh + (size_t)(gm0 + srow) * DM + sslot * 8;
    const f16* Bg = wq + (size_t)(gn0 + srow) * DM + sslot * 8;

    int aoff[4][2], boff[4][2];
#pragma unroll
    for (int i = 0; i < 4; ++i) {
        int Ra = wm + i * 16 + r15;
        aoff[i][0] = Ra * 64 + ((cs ^ (Ra & 7)) * 8);
        aoff[i][1] = Ra * 64 + (((cs + 4) ^ (Ra & 7)) * 8);
        int Rb = wn + i * 16 + r15;
        boff[i][0] = Rb * 64 + ((cs ^ (Rb & 7)) * 8);
        boff[i][1] = Rb * 64 + (((cs + 4) ^ (Rb & 7)) * 8);
    }
    f32x4 acc[4][4] = {};

    for (int k0 = 0; k0 < DM; k0 += 64) {
        __syncthreads();
#pragma unroll
        for (int j = 0; j < 4; ++j) {
            int c = w * 4 + j;
            gll16(Ag + (size_t)c * 8 * DM + k0, As + c * 512);
            gll16(Bg + (size_t)c * 8 * DM + k0, Bs + c * 512);
        }
        __syncthreads();
#pragma unroll
        for (int half = 0; half < 2; ++half) {
            f16x8 af[4], bf[4];
#pragma unroll
            for (int i = 0; i < 4; ++i) af[i] = *(const f16x8*)&As[aoff[i][half]];
#pragma unroll
            for (int i = 0; i < 4; ++i) bf[i] = *(const f16x8*)&Bs[boff[i][half]];
#pragma unroll
            for (int mi = 0; mi < 4; ++mi)
#pragma unroll
                for (int ni = 0; ni < 4; ++ni)
                    acc[mi][ni] = __builtin_amdgcn_mfma_f32_16x16x32_f16(af[mi], bf[ni], acc[mi][ni], 0, 0, 0);
        }
    }

    // ---- epilogue: LDS transpose, coalesced f16x8 stores ----
    const int which = gn0 >> 10;  // block-uniform
    const int CSTR = (which == 2) ? 137 : 136;
    __syncthreads();
#pragma unroll
    for (int ni = 0; ni < 4; ++ni) {
        int jcolp = gn0 + wn + ni * 16 + r15;
        int rr = jcolp & 1023, hh = rr >> 6, dd = rr & 63;
        float bb = bqkv[hh * 192 + dd * 3 + which];
#pragma unroll
        for (int mi = 0; mi < 4; ++mi)
#pragma unroll
            for (int jj = 0; jj < 4; ++jj)
                Cs[(wm + mi * 16 + cs * 4 + jj) * CSTR + (wn + ni * 16 + r15)] =
                    (f16)(acc[mi][ni][jj] + bb);
    }
    __syncthreads();
    const int bglob = gm0 >> 10;
    const int sbase = gm0 & 1023;
    if (which < 2) {
        f16* dstb = qk + (size_t)which * (Bb * Hh) * (Ss * DH);
#pragma unroll
        for (int it = 0; it < 8; ++it) {
            int lin = it * 2048 + t * 8;
            int row = lin >> 7, c0 = lin & 127;
            f16x8 v = *(const f16x8*)&Cs[row * 136 + c0];
            int rr = (gn0 + c0) & 1023;
            int hh = rr >> 6, d0 = rr & 63;
            *(f16x8*)(dstb + ((size_t)(bglob * Hh + hh)) * (Ss * DH) +
                      (size_t)(sbase + row) * DH + d0) = v;
        }
    } else {
#pragma unroll
        for (int it = 0; it < 8; ++it) {
            int col = it * 16 + (t >> 4);
            int s0 = (t & 15) * 8;
            f16x8 v;
#pragma unroll
            for (int e = 0; e < 8; ++e) v[e] = Cs[(s0 + e) * 137 + col];
            int rr = (gn0 + col) & 1023;
            int hh = rr >> 6, dd = rr & 63;
            *(f16x8*)(vT + ((size_t)(bglob * Hh + hh) * DH + dd) * Ss + sbase + s0) = v;
        }
    }
}

// ---------------- K3a: column stats; 128-row Q chunks, dbuf, paired strips ----------------
// grid: (4, 128) x 512 threads; paired k-strips (si, 7-si)
__launch_bounds__(512, 2)
__global__ void colstats_kernel(const f16* __restrict__ qk, float* __restrict__ cbuf) {
    __shared__ __align__(16) f16 Qs[2][128 * 64];  // 32KB
    const int t = threadIdx.x, lane = t & 63, w = t >> 6;
    const int r15 = lane & 15, cs = lane >> 4;
    const int srow = lane >> 3, sslot = (lane & 7) ^ srow;
    const int bh = blockIdx.y, si = blockIdx.x;
    const int kA0 = si * 128, kB0 = (7 - si) * 128;
    const size_t hs = (size_t)(Bb * Hh) * (Ss * DH);
    const f16* qb = qk + (size_t)bh * (Ss * DH);
    const f16* kb = qb + hs;

    const int kwA = kA0 + w * 16, kglobA = kwA + r15;
    const int kwB = kB0 + w * 16, kglobB = kwB + r15;
    f16x8 kfA0 = *(const f16x8*)(kb + (size_t)(kwA + r15) * DH + cs * 8);
    f16x8 kfA1 = *(const f16x8*)(kb + (size_t)(kwA + r15) * DH + 32 + cs * 8);
    f16x8 kfB0 = *(const f16x8*)(kb + (size_t)(kwB + r15) * DH + cs * 8);
    f16x8 kfB1 = *(const f16x8*)(kb + (size_t)(kwB + r15) * DH + 32 + cs * 8);

    gll16(qb + (size_t)(si * 128 + w * 16 + srow) * DH + sslot * 8, Qs[0] + (2 * w) * 512);
    gll16(qb + (size_t)(si * 128 + w * 16 + 8 + srow) * DH + sslot * 8, Qs[0] + (2 * w + 1) * 512);
    __syncthreads();
    float la = 0.0f, lb = 0.0f;
    int cur = 0;

    for (int qt2 = si; qt2 < 8; ++qt2) {
        if (qt2 + 1 < 8) {
            gll16(qb + (size_t)((qt2 + 1) * 128 + w * 16 + srow) * DH + sslot * 8,
                  Qs[cur ^ 1] + (2 * w) * 512);
            gll16(qb + (size_t)((qt2 + 1) * 128 + w * 16 + 8 + srow) * DH + sslot * 8,
                  Qs[cur ^ 1] + (2 * w + 1) * 512);
        }
#pragma unroll
        for (int qs = 0; qs < 8; ++qs) {
            const int qb16 = qt2 * 128 + qs * 16;
            const bool nA = (qb16 + 15 >= kwA);
            const bool nB = (qb16 + 15 >= kwB);
            if (!(nA || nB)) continue;
            int Ra = qs * 16 + r15;
            f16x8 a0 = *(const f16x8*)&Qs[cur][Ra * 64 + ((cs ^ (Ra & 7)) * 8)];
            f16x8 a1 = *(const f16x8*)&Qs[cur][Ra * 64 + (((cs + 4) ^ (Ra & 7)) * 8)];
            if (nA) {
                f32x4 sf = {};
                sf = __builtin_amdgcn_mfma_f32_16x16x32_f16(a0, kfA0, sf, 0, 0, 0);
                sf = __builtin_amdgcn_mfma_f32_16x16x32_f16(a1, kfA1, sf, 0, 0, 0);
#pragma unroll
                for (int j = 0; j < 4; ++j) {
                    int q = qb16 + cs * 4 + j;
                    la += (q >= kglobA) ? __expf(sf[j]) : 0.0f;
                }
            }
            if (nB) {
                f32x4 sf = {};
                sf = __builtin_amdgcn_mfma_f32_16x16x32_f16(a0, kfB0, sf, 0, 0, 0);
                sf = __builtin_amdgcn_mfma_f32_16x16x32_f16(a1, kfB1, sf, 0, 0, 0);
#pragma unroll
                for (int j = 0; j < 4; ++j) {
                    int q = qb16 + cs * 4 + j;
                    lb += (q >= kglobB) ? __expf(sf[j]) : 0.0f;
                }
            }
        }
        __syncthreads();
        cur ^= 1;
    }
    la += __shfl_xor(la, 16, 64);
    la += __shfl_xor(la, 32, 64);
    lb += __shfl_xor(lb, 16, 64);
    lb += __shfl_xor(lb, 32, 64);
    if (cs == 0) {
        cbuf[bh * Ss + kglobA] = logf(la);
        cbuf[bh * Ss + kglobB] = logf(lb);
    }
}

// ---------------- K3b: attnz; sequential strips (lower VGPR), K/V staged + shared ----------------
// grid: (4, 128) x 512 threads; paired q-strips (si, 7-si)
__launch_bounds__(512, 2)
__global__ void attnz_kernel(const f16* __restrict__ qk, const f16* __restrict__ vT,
                             const float* __restrict__ cbuf, f16* __restrict__ z) {
    __shared__ __align__(16) f16 Ks[64 * 64];
    __shared__ __align__(16) f16 Vs[64 * 64];
    __shared__ __align__(16) float cb[1024];
    const int t = threadIdx.x, lane = t & 63, w = t >> 6;
    const int r15 = lane & 15, cs = lane >> 4;
    const int srow = lane >> 3, sslot = (lane & 7) ^ srow;
    const int bh = blockIdx.y, si = blockIdx.x;
    const int qtA = si, qtB = 7 - si;
    const size_t hs = (size_t)(Bb * Hh) * (Ss * DH);
    const f16* qb = qk + (size_t)bh * (Ss * DH);
    const f16* kb = qb + hs;
    const f16* vb = vT + (size_t)bh * (DH * Ss);

    const int qwA = qtA * 128 + w * 16, qA = qwA + r15;
    const int qwB = qtB * 128 + w * 16, qB = qwB + r15;
    f16x8 aqA0 = *(const f16x8*)(qb + (size_t)(qwA + r15) * DH + cs * 8);
    f16x8 aqA1 = *(const f16x8*)(qb + (size_t)(qwA + r15) * DH + 32 + cs * 8);
    f16x8 aqB0 = *(const f16x8*)(qb + (size_t)(qwB + r15) * DH + cs * 8);
    f16x8 aqB1 = *(const f16x8*)(qb + (size_t)(qwB + r15) * DH + 32 + cs * 8);

    gll16(kb + (size_t)(w * 8 + srow) * DH + sslot * 8, Ks + w * 512);
    gll16(vb + (size_t)(w * 8 + srow) * Ss + sslot * 8, Vs + w * 512);
    {
        float2 c2 = *(const float2*)(cbuf + bh * Ss + t * 2);
        *(float2*)&cb[t * 2] = c2;
    }
    __syncthreads();
    f32x4 accA[4] = {}, accB[4] = {};
    const int nktA = 2 * qtA + 2, nktB = 2 * qtB + 2;
    const int sAl = ((cs & 1) * 2) * 16 + r15;
    const int sBl = sAl + 16;
    const bool hi = (cs >> 1) != 0;

    for (int kt = 0; kt < nktB; ++kt) {
        if (kt) {
            __syncthreads();
            gll16(kb + (size_t)(kt * 64 + w * 8 + srow) * DH + sslot * 8, Ks + w * 512);
            gll16(vb + (size_t)(w * 8 + srow) * Ss + kt * 64 + sslot * 8, Vs + w * 512);
            __syncthreads();
        }
        const int kb0 = kt * 64;
        const bool doA = (kt < nktA) && (kb0 <= qwA + 15);
        const bool doB = (kb0 <= qwB + 15);
        if (!(doA || doB)) continue;

        // ---------- strip A (complete: QK^T -> P -> shfl -> PV) ----------
        if (doA) {
            unsigned pk[4][2];
#pragma unroll
            for (int tl = 0; tl < 4; ++tl) {
                const int kbase = kb0 + tl * 16;
                pk[tl][0] = 0u; pk[tl][1] = 0u;
                if (kbase > qwA + 15) continue;
                int Rk2 = tl * 16 + r15;
                f16x8 kf0 = *(const f16x8*)&Ks[Rk2 * 64 + ((cs ^ (Rk2 & 7)) * 8)];
                f16x8 kf1 = *(const f16x8*)&Ks[Rk2 * 64 + (((cs + 4) ^ (Rk2 & 7)) * 8)];
                f32x4 cv = *(const f32x4*)&cb[kbase + cs * 4];
                f32x4 sf = {};
                __builtin_amdgcn_s_setprio(1);
                sf = __builtin_amdgcn_mfma_f32_16x16x32_f16(kf0, aqA0, sf, 0, 0, 0);
                sf = __builtin_amdgcn_mfma_f32_16x16x32_f16(kf1, aqA1, sf, 0, 0, 0);
                __builtin_amdgcn_s_setprio(0);
                f16 p[4];
#pragma unroll
                for (int j = 0; j < 4; ++j) {
                    int k = kbase + cs * 4 + j;
                    p[j] = (f16)((k <= qA) ? __expf(sf[j] - cv[j]) : 0.0f);
                }
                union { f16 h[2]; unsigned u; } u0, u1;
                u0.h[0] = p[0]; u0.h[1] = p[1];
                u1.h[0] = p[2]; u1.h[1] = p[3];
                pk[tl][0] = u0.u; pk[tl][1] = u1.u;
            }
#pragma unroll
            for (int c = 0; c < 2; ++c) {
                if (kb0 + c * 32 > qwA + 15) continue;
                unsigned a0 = (unsigned)__shfl((int)pk[2 * c][0], sAl, 64);
                unsigned a1 = (unsigned)__shfl((int)pk[2 * c][1], sAl, 64);
                unsigned a2 = (unsigned)__shfl((int)pk[2 * c][0], sBl, 64);
                unsigned a3 = (unsigned)__shfl((int)pk[2 * c][1], sBl, 64);
                unsigned b0_ = (unsigned)__shfl((int)pk[2 * c + 1][0], sAl, 64);
                unsigned b1_ = (unsigned)__shfl((int)pk[2 * c + 1][1], sAl, 64);
                unsigned b2_ = (unsigned)__shfl((int)pk[2 * c + 1][0], sBl, 64);
                unsigned b3_ = (unsigned)__shfl((int)pk[2 * c + 1][1], sBl, 64);
                union { unsigned u[4]; f16x8 v; } bf;
                bf.u[0] = hi ? b0_ : a0;
                bf.u[1] = hi ? b1_ : a1;
                bf.u[2] = hi ? b2_ : a2;
                bf.u[3] = hi ? b3_ : a3;
                __builtin_amdgcn_s_setprio(1);
#pragma unroll
                for (int dt = 0; dt < 4; ++dt) {
                    int Rv = dt * 16 + r15;
                    f16x8 vf = *(const f16x8*)&Vs[Rv * 64 + (((4 * c + cs) ^ (Rv & 7)) * 8)];
                    accA[dt] = __builtin_amdgcn_mfma_f32_16x16x32_f16(vf, bf.v, accA[dt], 0, 0, 0);
                }
                __builtin_amdgcn_s_setprio(0);
            }
        }
        // ---------- strip B ----------
        if (doB) {
            unsigned pk[4][2];
#pragma unroll
            for (int tl = 0; tl < 4; ++tl) {
                const int kbase = kb0 + tl * 16;
                pk[tl][0] = 0u; pk[tl][1] = 0u;
                if (kbase > qwB + 15) continue;
                int Rk2 = tl * 16 + r15;
                f16x8 kf0 = *(const f16x8*)&Ks[Rk2 * 64 + ((cs ^ (Rk2 & 7)) * 8)];
                f16x8 kf1 = *(const f16x8*)&Ks[Rk2 * 64 + (((cs + 4) ^ (Rk2 & 7)) * 8)];
                f32x4 cv = *(const f32x4*)&cb[kbase + cs * 4];
                f32x4 sf = {};
                __builtin_amdgcn_s_setprio(1);
                sf = __builtin_amdgcn_mfma_f32_16x16x32_f16(kf0, aqB0, sf, 0, 0, 0);
                sf = __builtin_amdgcn_mfma_f32_16x16x32_f16(kf1, aqB1, sf, 0, 0, 0);
                __builtin_amdgcn_s_setprio(0);
                f16 p[4];
#pragma unroll
                for (int j = 0; j < 4; ++j) {
                    int k = kbase + cs * 4 + j;
                    p[j] = (f16)((k <= qB) ? __expf(sf[j] - cv[j]) : 0.0f);
                }
                union { f16 h[2]; unsigned u; } u0, u1;
                u0.h[0] = p[0]; u0.h[1] = p[1];
                u1.h[0] = p[2]; u1.h[1] = p[3];
                pk[tl][0] = u0.u; pk[tl][1] = u1.u;
            }
#pragma unroll
            for (int c = 0; c < 2; ++c) {
                if (kb0 + c * 32 > qwB + 15) continue;
                unsigned a0 = (unsigned)__shfl((int)pk[2 * c][0], sAl, 64);
                unsigned a1 = (unsigned)__shfl((int)pk[2 * c][1], sAl, 64);
                unsigned a2 = (unsigned)__shfl((int)pk[2 * c][0], sBl, 64);
                unsigned a3 = (unsigned)__shfl((int)pk[2 * c][1], sBl, 64);
                unsigned b0_ = (unsigned)__shfl((int)pk[2 * c + 1][0], sAl, 64);
                unsigned b1_ = (unsigned)__shfl((int)pk[2 * c + 1][1], sAl, 64);
                unsigned b2_ = (unsigned)__shfl((int)pk[2 * c + 1][0], sBl, 64);
                unsigned b3_ = (unsigned)__shfl((int)pk[2 * c + 1][1], sBl, 64);
                union { unsigned u[4]; f16x8 v; } bf;
                bf.u[0] = hi ? b0_ : a0;
                bf.u[1] = hi ? b1_ : a1;
                bf.u[2] = hi ? b2_ : a2;
                bf.u[3] = hi ? b3_ : a3;
                __builtin_amdgcn_s_setprio(1);
#pragma unroll
                for (int dt = 0; dt < 4; ++dt) {
                    int Rv = dt * 16 + r15;
                    f16x8 vf = *(const f16x8*)&Vs[Rv * 64 + (((4 * c + cs) ^ (Rv & 7)) * 8)];
                    accB[dt] = __builtin_amdgcn_mfma_f32_16x16x32_f16(vf, bf.v, accB[dt], 0, 0, 0);
                }
                __builtin_amdgcn_s_setprio(0);
            }
        }
    }
    const int b = bh >> 4, h = bh & 15;
#pragma unroll
    for (int dt = 0; dt < 4; ++dt) {
        f16x4 zvA = {(f16)accA[dt][0], (f16)accA[dt][1], (f16)accA[dt][2], (f16)accA[dt][3]};
        *(f16x4*)(z + ((size_t)(b * Ss + qA)) * DM + h * DH + dt * 16 + cs * 4) = zvA;
        f16x4 zvB = {(f16)accB[dt][0], (f16)accB[dt][1], (f16)accB[dt][2], (f16)accB[dt][3]};
        *(f16x4*)(z + ((size_t)(b * Ss + qB)) * DM + h * DH + dt * 16 + cs * 4) = zvB;
    }
}

// ---------------- K4: output projection (m97 + f32 LDS-transpose epilogue) ----------------
__launch_bounds__(256, 2)
__global__ void out_gemm(const f16* __restrict__ z, const f16* __restrict__ wo,
                         const float* __restrict__ bo, float* __restrict__ out) {
    __shared__ __align__(16) char smem[128 * 132 * 4];  // 67584B; As/Bs then Cs(f32)
    f16* As = (f16*)smem;
    f16* Bs = (f16*)(smem + 16384);
    float* Cs = (float*)smem;
    const int t = threadIdx.x, lane = t & 63, w = t >> 6;
    const int bid = blockIdx.y * gridDim.x + blockIdx.x;
    const int swz = (bid & 7) * 64 + (bid >> 3);
    const int gm0 = (swz / 8) * 128, gn0 = (swz % 8) * 128;
    const int wm = (w >> 1) * 64, wn = (w & 1) * 64;
    const int srow = lane >> 3, sslot = (lane & 7) ^ srow;
    const int r15 = lane & 15, cs = lane >> 4;

    const f16* Ag = z + (size_t)(gm0 + srow) * DM + sslot * 8;
    const f16* Bg = wo + (size_t)(gn0 + srow) * DM + sslot * 8;

    int aoff[4][2], boff[4][2];
#pragma unroll
    for (int i = 0; i < 4; ++i) {
        int Ra = wm + i * 16 + r15;
        aoff[i][0] = Ra * 64 + ((cs ^ (Ra & 7)) * 8);
        aoff[i][1] = Ra * 64 + (((cs + 4) ^ (Ra & 7)) * 8);
        int Rb = wn + i * 16 + r15;
        boff[i][0] = Rb * 64 + ((cs ^ (Rb & 7)) * 8);
        boff[i][1] = Rb * 64 + (((cs + 4) ^ (Rb & 7)) * 8);
    }
    f32x4 acc[4][4] = {};

    for (int k0 = 0; k0 < DM; k0 += 64) {
        __syncthreads();
#pragma unroll
        for (int j = 0; j < 4; ++j) {
            int c = w * 4 + j;
            gll16(Ag + (size_t)c * 8 * DM + k0, As + c * 512);
            gll16(Bg + (size_t)c * 8 * DM + k0, Bs + c * 512);
        }
        __syncthreads();
#pragma unroll
        for (int half = 0; half < 2; ++half) {
            f16x8 af[4], bf[4];
#pragma unroll
            for (int i = 0; i < 4; ++i) af[i] = *(const f16x8*)&As[aoff[i][half]];
#pragma unroll
            for (int i = 0; i < 4; ++i) bf[i] = *(const f16x8*)&Bs[boff[i][half]];
#pragma unroll
            for (int mi = 0; mi < 4; ++mi)
#pragma unroll
                for (int ni = 0; ni < 4; ++ni)
                    acc[mi][ni] = __builtin_amdgcn_mfma_f32_16x16x32_f16(af[mi], bf[ni], acc[mi][ni], 0, 0, 0);
        }
    }
    // ---- epilogue: f32 LDS transpose -> coalesced float4 stores ----
    __syncthreads();
#pragma unroll
    for (int ni = 0; ni < 4; ++ni) {
        float bb = bo[gn0 + wn + ni * 16 + r15];
#pragma unroll
        for (int mi = 0; mi < 4; ++mi)
#pragma unroll
            for (int jj = 0; jj < 4; ++jj)
                Cs[(wm + mi * 16 + cs * 4 + jj) * 132 + (wn + ni * 16 + r15)] =
                    acc[mi][ni][jj] + bb;
    }
    __syncthreads();
#pragma unroll
    for (int it = 0; it < 16; ++it) {
        int idx = it * 256 + t;
        int row = idx >> 5, c0 = (idx & 31) * 4;
        float4 v = *(const float4*)&Cs[row * 132 + c0];
        *(float4*)(out + (size_t)(gm0 + row) * DM + gn0 + c0) = v;
    }
}

extern "C" void kernel_launch(void* const* d_in, const int* in_sizes, int n_in,
                              void* d_out, int out_size, void* d_ws, size_t ws_size,
                              hipStream_t stream) {
    (void)in_sizes; (void)n_in; (void)out_size; (void)ws_size;
    const float* x    = (const float*)d_in[0];
    const float* Wqkv = (const float*)d_in[1];
    const float* bqkv = (const float*)d_in[2];
    const float* Wo   = (const float*)d_in[3];
    const float* bo   = (const float*)d_in[4];
    float* out = (float*)d_out;

    char* ws = (char*)d_ws;
    f16* xh   = (f16*)ws;                       // 16,777,216
    f16* z    = (f16*)ws;                       // reuse (xh dead after qkv gemm)
    f16* wq   = (f16*)(ws + 16777216);          //  6,291,456 (row-permuted)
    f16* wo   = (f16*)(ws + 23068672);          //  2,097,152
    f16* qk   = (f16*)(ws + 25165824);          // 33,554,432
    f16* vT   = (f16*)(ws + 58720256);          // 16,777,216
    float* cbuf = (float*)(ws + 75497472);      //    524,288

    prep_kernel<<<Mm + N3 + DM, 256, 0, stream>>>(x, xh, Wqkv, Wo, wq, wo);
    qkv_gemm<<<dim3(N3 / 128, Mm / 128), 256, 0, stream>>>(xh, wq, bqkv, qk, vT);
    colstats_kernel<<<dim3(4, Bb * Hh), 512, 0, stream>>>(qk, cbuf);
    attnz_kernel<<<dim3(4, Bb * Hh), 512, 0, stream>>>(qk, vT, cbuf, z);
    out_gemm<<<dim3(DM / 128, Mm / 128), 256, 0, stream>>>(z, wo, bo, out);
}